// Round 1
// baseline (139.713 us; speedup 1.0000x reference)
//
#include <hip/hip_runtime.h>

#define DIM   64
#define HW    4096      // 64*64 spatial per batch
#define NSAMP 65536
#define NEMB  1024

// ---------------- init: zero counts + errsum ----------------
__global__ __launch_bounds__(1024) void vq_init(unsigned int* counts, float* errsum) {
    int t = threadIdx.x;
    if (t < NEMB) counts[t] = 0u;
    if (t == 0) *errsum = 0.0f;
}

// ---------------- main: argmin + gather + out write ----------------
// grid 512, block 256. Each block: 128 samples (same batch, contiguous hw).
// LDS: zt[128][64] (swizzled), et[128][64] (swizzled) -> 66KB -> 2 blocks/CU.
__global__ __launch_bounds__(256, 2) void vq_main(
    const float* __restrict__ z, const float* __restrict__ emb,
    float* __restrict__ out, unsigned int* __restrict__ counts,
    float* __restrict__ errsum)
{
    __shared__ float zt[128 * 64];   // row n_loc: 256B, chunk dc stored at dc ^ ((n>>3)&3)
    __shared__ float et[128 * 64];   // row k_loc: 256B, chunk dc stored at dc ^ (k>>3)
    __shared__ float znorm_s[128];
    __shared__ float enorm_s[128];
    __shared__ float md_sh[128];
    __shared__ int   idx_sh[128];

    const int t   = threadIdx.x;
    const int n0  = blockIdx.x * 128;
    const int bb  = n0 >> 12;        // batch index
    const int hw0 = n0 & 4095;
    const float* zb = z + bb * (DIM * HW) + hw0;   // + d*HW + x

    // ---- stage z tile: global [d][x] -> LDS [x][d] (swizzled), transpose in regs ----
    {
        const int x  = t & 127;
        const int g  = t >> 7;
        const int sx = (x >> 3) & 3;
        #pragma unroll
        for (int it = 0; it < 8; ++it) {
            const int dc = g * 8 + it;
            float4 v;
            v.x = zb[(dc * 4 + 0) * HW + x];
            v.y = zb[(dc * 4 + 1) * HW + x];
            v.z = zb[(dc * 4 + 2) * HW + x];
            v.w = zb[(dc * 4 + 3) * HW + x];
            *(float4*)&zt[x * 64 + ((dc ^ sx) << 2)] = v;
        }
    }
    __syncthreads();

    // ---- znorm, replicating numpy pairwise-8 accumulator order ----
    if (t < 128) {
        const int x  = t;
        const int sx = (x >> 3) & 3;
        float a[8] = {0,0,0,0,0,0,0,0};
        #pragma unroll
        for (int dc = 0; dc < 16; ++dc) {
            float4 v = *(const float4*)&zt[x * 64 + ((dc ^ sx) << 2)];
            a[(4*dc+0) & 7] += v.x * v.x;
            a[(4*dc+1) & 7] += v.y * v.y;
            a[(4*dc+2) & 7] += v.z * v.z;
            a[(4*dc+3) & 7] += v.w * v.w;
        }
        znorm_s[x] = ((a[0]+a[1]) + (a[2]+a[3])) + ((a[4]+a[5]) + (a[6]+a[7]));
    }
    __syncthreads();

    const int kl = t & 15;   // k-lane group
    const int ng = t >> 4;   // n-group (0..15)
    const int sz = ng & 3;

    float zn[8];
    #pragma unroll
    for (int i = 0; i < 8; ++i) zn[i] = znorm_s[ng * 8 + i];

    float mval[8];
    int   midx[8];
    #pragma unroll
    for (int i = 0; i < 8; ++i) { mval[i] = __builtin_inff(); midx[i] = 0; }

    for (int kt = 0; kt < 8; ++kt) {
        const int kbase = kt * 128;

        // stage e tile (swizzled rows)
        #pragma unroll
        for (int ii = 0; ii < 8; ++ii) {
            const int ci = ii * 256 + t;          // 0..2047 chunk id
            const int r  = ci >> 4;
            const int dc = ci & 15;
            float4 v = *(const float4*)&emb[(kbase + r) * 64 + dc * 4];
            *(float4*)&et[r * 64 + ((dc ^ (r >> 3)) << 2)] = v;
        }
        // enorm for this tile (from global, L2-hot), numpy pairwise-8 order
        if (t < 128) {
            const float* e = emb + (kbase + t) * 64;
            float a[8] = {0,0,0,0,0,0,0,0};
            #pragma unroll
            for (int d8 = 0; d8 < 8; ++d8) {
                #pragma unroll
                for (int j = 0; j < 8; ++j) { float ev = e[d8*8 + j]; a[j] += ev * ev; }
            }
            enorm_s[t] = ((a[0]+a[1]) + (a[2]+a[3])) + ((a[4]+a[5]) + (a[6]+a[7]));
        }
        __syncthreads();

        float en[8];
        #pragma unroll
        for (int j = 0; j < 8; ++j) en[j] = enorm_s[kl * 8 + j];

        float acc[8][8];
        #pragma unroll
        for (int i = 0; i < 8; ++i)
            #pragma unroll
            for (int j = 0; j < 8; ++j) acc[i][j] = 0.0f;

        // dot products: sequential ascending-d FMA chain (matches BLAS microkernel order)
        #pragma unroll 2
        for (int dc = 0; dc < 16; ++dc) {
            float4 zf[8], ef[8];
            #pragma unroll
            for (int i = 0; i < 8; ++i)
                zf[i] = *(const float4*)&zt[(ng*8+i)*64 + ((dc ^ sz) << 2)];
            #pragma unroll
            for (int j = 0; j < 8; ++j)
                ef[j] = *(const float4*)&et[(kl*8+j)*64 + ((dc ^ kl) << 2)];
            #pragma unroll
            for (int i = 0; i < 8; ++i) {
                #pragma unroll
                for (int j = 0; j < 8; ++j) {
                    acc[i][j] = fmaf(zf[i].x, ef[j].x, acc[i][j]);
                    acc[i][j] = fmaf(zf[i].y, ef[j].y, acc[i][j]);
                    acc[i][j] = fmaf(zf[i].z, ef[j].z, acc[i][j]);
                    acc[i][j] = fmaf(zf[i].w, ef[j].w, acc[i][j]);
                }
            }
        }

        // distances + running argmin (ascending k, strict < => first-index tie-break)
        #pragma unroll
        for (int j = 0; j < 8; ++j) {
            const int kg = kbase + kl * 8 + j;
            #pragma unroll
            for (int i = 0; i < 8; ++i) {
                const float tt   = zn[i] + en[j];                 // fp32 add, as ref
                const float dist = fmaf(-2.0f, acc[i][j], tt);    // == fp32(t - 2*dot), 2*dot exact
                if (dist < mval[i]) { mval[i] = dist; midx[i] = kg; }
            }
        }
        __syncthreads();
    }

    // ---- cross-lane argmin over the 16 k-lanes (tie-break: smaller k) ----
    #pragma unroll
    for (int i = 0; i < 8; ++i) {
        float m = mval[i]; int id = midx[i];
        #pragma unroll
        for (int mask = 1; mask <= 8; mask <<= 1) {
            float m2 = __shfl_xor(m, mask, 64);
            int   i2 = __shfl_xor(id, mask, 64);
            if (m2 < m || (m2 == m && i2 < id)) { m = m2; id = i2; }
        }
        if (kl == 0) { md_sh[ng*8 + i] = m; idx_sh[ng*8 + i] = id; }
    }
    __syncthreads();

    // ---- histogram + error sum (min distance == ||z-e||^2) ----
    if (t < 128) atomicAdd(&counts[idx_sh[t]], 1u);
    if (t < 64) {
        float s = md_sh[t] + md_sh[t + 64];
        #pragma unroll
        for (int off = 32; off >= 1; off >>= 1) s += __shfl_down(s, off, 64);
        if (t == 0) atomicAdd(errsum, s);
    }

    // ---- epilogue: out[b,c,h,w] = z + (q - z), exact ref rounding ----
    {
        const int x  = t & 127;
        const int cg = t >> 7;
        const int sx = (x >> 3) & 3;
        const int idx = idx_sh[x];
        const float* er = emb + idx * 64;
        float* ob = out + bb * (DIM * HW) + hw0 + x;
        #pragma unroll
        for (int cq = 0; cq < 8; ++cq) {
            const int c  = cg * 32 + cq * 4;
            const int dc = c >> 2;
            float4 e4 = *(const float4*)&er[c];
            float4 z4 = *(const float4*)&zt[x * 64 + ((dc ^ sx) << 2)];
            ob[(c+0) * HW] = z4.x + (e4.x - z4.x);
            ob[(c+1) * HW] = z4.y + (e4.y - z4.y);
            ob[(c+2) * HW] = z4.z + (e4.z - z4.z);
            ob[(c+3) * HW] = z4.w + (e4.w - z4.w);
        }
    }
}

// ---------------- finalize: scalars ----------------
__global__ __launch_bounds__(256) void vq_fin(const unsigned int* __restrict__ counts,
                                              const float* __restrict__ errsum,
                                              float* __restrict__ scal)
{
    __shared__ float part[4];
    const int t = threadIdx.x;
    float s = 0.0f;
    for (int k = t; k < NEMB; k += 256) {
        float p = (float)counts[k] * (1.0f / 65536.0f);
        s += p * logf(p + 1e-10f);
    }
    #pragma unroll
    for (int off = 32; off >= 1; off >>= 1) s += __shfl_down(s, off, 64);
    if ((t & 63) == 0) part[t >> 6] = s;
    __syncthreads();
    if (t == 0) {
        float tot = (part[0] + part[1]) + (part[2] + part[3]);
        float es  = *errsum;
        scal[0] = 1.25f * (es * (1.0f / 4194304.0f));  // loss = 1.25 * mse
        scal[1] = expf(-tot);                          // perplexity
        scal[2] = es * (1.0f / 65536.0f);              // avg_error
    }
}

extern "C" void kernel_launch(void* const* d_in, const int* in_sizes, int n_in,
                              void* d_out, int out_size, void* d_ws, size_t ws_size,
                              hipStream_t stream) {
    const float* z   = (const float*)d_in[0];
    const float* emb = (const float*)d_in[1];
    float* out = (float*)d_out;
    unsigned int* counts = (unsigned int*)d_ws;
    float* errsum = (float*)((char*)d_ws + 4096);

    vq_init<<<1, 1024, 0, stream>>>(counts, errsum);
    vq_main<<<512, 256, 0, stream>>>(z, emb, out, counts, errsum);
    vq_fin<<<1, 256, 0, stream>>>(counts, errsum, out + 4194304);
}